// Round 1
// baseline (29.910 us; speedup 1.0000x reference)
//
#include <hip/hip_runtime.h>

// FastGuidedFilter on MI355X — round 7: occupancy + granularity.
// Round-6 was latency-bound (VALUBusy 15.6%, HBM 20%, Occupancy 35%):
// LDS 25.5 KiB capped residency at 6 blocks/CU and the 2160-block grid
// (8.4/CU) left a long low-occupancy tail. This round:
//   * ROWS 8->5, RSETS 4->3 (vertical tent index t < 1.99 => 3 slots suffice)
//   * TILE_W 256->240: 1920/240 = 8 uniform tiles, phases single-pass,
//     rs/cs via shifts (VCOLS=64).
//   * LDS 18240 B => 8 blocks/CU (wave cap, 32/32 waves); forced via
//     __launch_bounds__(256, 8) (64-VGPR budget; phase C holds 3 lerp
//     pairs + xr[5] ~ 55 live VGPRs).
//   * Grid 3456 blocks (finer packing, smaller tail).
// Structure otherwise identical to the verified round-6 kernel:
//   Phase A: 3 rowsets x 64 cols vertical 3-tap sums {x,y,xy,xx} -> LDS
//   Phase B: 3 rowsets x 62 cols horizontal 3-tap -> (A,b) -> LDS
//   Phase C: hoisted horizontal lerp -> 3 (A,b) pairs/thread, then per row
//            3-slot tent-weight vertical combine + A*hr + b, nt stores.
// hr_x loads issued before phases A/B (issue-early).
//
// Shapes (NHWC, C=4 => one float4 per pixel):
//   lr_x, lr_y : (2, 270, 480, 4) f32
//   hr_x       : (2, 1080, 1920, 4) f32
//   out        : (2, 1080, 1920, 4) f32

namespace {

constexpr int LR_H = 270, LR_W = 480;
constexpr int A_H  = 268, A_W  = 478;   // VALID 3x3 output grid
constexpr int HR_H = 1080, HR_W = 1920;
constexpr int BATCH = 2;
constexpr float EPS_F = 1e-5f;

constexpr int TILE_W = 240;                 // HR px per block row (1920/240=8 exact)
constexpr int NTILES = HR_W / TILE_W;       // 8, uniform
constexpr int ROWS   = 5;                   // HR rows per block
constexpr int ROWGRP = HR_H / ROWS;         // 216, exact
constexpr int VCOLS  = 64;   // vertical-sum slots (A-cols + 2 taps); power of 2
constexpr int ACOLS  = 62;   // A/b slots (max wi = 60, +1 neighbor)
constexpr int RSETS  = 3;    // A-rowsets staged (5 rows: tent t in [0,2))

using f32x4 = __attribute__((ext_vector_type(4))) float;

__device__ __forceinline__ float4 f4add(float4 a, float4 b) {
    return make_float4(a.x + b.x, a.y + b.y, a.z + b.z, a.w + b.w);
}
__device__ __forceinline__ float4 f4sub(float4 a, float4 b) {
    return make_float4(a.x - b.x, a.y - b.y, a.z - b.z, a.w - b.w);
}
__device__ __forceinline__ float4 f4mul(float4 a, float4 b) {
    return make_float4(a.x * b.x, a.y * b.y, a.z * b.z, a.w * b.w);
}
__device__ __forceinline__ float4 f4scale(float4 a, float s) {
    return make_float4(a.x * s, a.y * s, a.z * s, a.w * s);
}
__device__ __forceinline__ float4 f4fma(float4 a, float4 b, float4 c) {
    return make_float4(fmaf(a.x, b.x, c.x), fmaf(a.y, b.y, c.y),
                       fmaf(a.z, b.z, c.z), fmaf(a.w, b.w, c.w));
}
__device__ __forceinline__ float4 f4lerp(float4 a, float4 b, float t) {
    return make_float4(fmaf(t, b.x - a.x, a.x), fmaf(t, b.y - a.y, a.y),
                       fmaf(t, b.z - a.z, a.z), fmaf(t, b.w - a.w, a.w));
}
// acc += s * v (scalar s)
__device__ __forceinline__ float4 f4axpy(float s, float4 v, float4 acc) {
    return make_float4(fmaf(s, v.x, acc.x), fmaf(s, v.y, acc.y),
                       fmaf(s, v.z, acc.z), fmaf(s, v.w, acc.w));
}
__device__ __forceinline__ float4 f4rcp(float4 a) {
    return make_float4(__builtin_amdgcn_rcpf(a.x), __builtin_amdgcn_rcpf(a.y),
                       __builtin_amdgcn_rcpf(a.z), __builtin_amdgcn_rcpf(a.w));
}
__device__ __forceinline__ void nt_store(float4 v, float4* p) {
    f32x4 rv = {v.x, v.y, v.z, v.w};
    __builtin_nontemporal_store(rv, (f32x4*)p);
}

} // namespace

__global__ __launch_bounds__(256, 8) void
fgf_fused5(const float4* __restrict__ lr_x,
           const float4* __restrict__ lr_y,
           const float4* __restrict__ hr_x,
           float4* __restrict__ out) {
    // [rowset][quantity x,y,xy,xx][col] — column-contiguous => conflict-free
    __shared__ float4 vs[RSETS][4][VCOLS];       // 12288 B
    __shared__ float4 sA4[RSETS][ACOLS];         //  2976 B
    __shared__ float4 sB4[RSETS][ACOLS];         //  2976 B => 18240 B total

    int bid  = blockIdx.x;
    int tile = bid & (NTILES - 1);   // NTILES = 8
    int g    = bid >> 3;
    int rg   = g % ROWGRP;
    int b    = g / ROWGRP;
    int tid  = threadIdx.x;

    // jax.image.resize bilinear (antialias=False): src = (i+0.5)*in/out - 0.5,
    // edge renormalization == index-clamped bilinear.
    constexpr float sh_scale = (float)A_H / (float)HR_H;   // 0.248148
    constexpr float sw_scale = (float)A_W / (float)HR_W;   // 0.248958

    int hbase = rg * ROWS;
    int R0 = (int)floorf((hbase + 0.5f) * sh_scale - 0.5f); // -1 at top edge

    int w_start = tile * TILE_W;
    int c0 = (int)floorf((w_start + 0.5f) * sw_scale - 0.5f); // -1 at left edge

    // ---- Issue hr_x loads early (latency hides under phases A/B).
    int w = w_start + tid;
    bool valid = (tid < TILE_W);
    size_t hr_row0 = ((size_t)b * HR_H + hbase) * (size_t)HR_W + w;
    float4 xr[ROWS];
#pragma unroll
    for (int j = 0; j < ROWS; ++j) {
        xr[j] = valid ? hr_x[hr_row0 + (size_t)j * HR_W]
                      : make_float4(0.f, 0.f, 0.f, 0.f);
    }

    // ---- Phase A: vertical 3-tap sums, RSETS x VCOLS = 192 tasks, one pass.
    if (tid < RSETS * VCOLS) {
        int rs = tid >> 6;                             // VCOLS = 64
        int cs = tid & 63;
        int ar = min(max(R0 + rs, 0), A_H - 1);        // A-row this set serves
        int col = min(max(c0 + cs, 0), LR_W - 1);      // lr col (clamped)
        const float4* px = lr_x + ((size_t)b * LR_H + ar) * LR_W + col;
        const float4* py = lr_y + ((size_t)b * LR_H + ar) * LR_W + col;
        float4 sx  = make_float4(0.f, 0.f, 0.f, 0.f);
        float4 sy  = make_float4(0.f, 0.f, 0.f, 0.f);
        float4 sxy = make_float4(0.f, 0.f, 0.f, 0.f);
        float4 sxx = make_float4(0.f, 0.f, 0.f, 0.f);
#pragma unroll
        for (int dy = 0; dy < 3; ++dy) {
            float4 x = px[(size_t)dy * LR_W];
            float4 y = py[(size_t)dy * LR_W];
            sx  = f4add(sx, x);
            sy  = f4add(sy, y);
            sxy = f4fma(x, y, sxy);
            sxx = f4fma(x, x, sxx);
        }
        vs[rs][0][cs] = sx;
        vs[rs][1][cs] = sy;
        vs[rs][2][cs] = sxy;
        vs[rs][3][cs] = sxx;
    }
    __syncthreads();

    // ---- Phase B: horizontal 3-tap -> A,b per rowset.
    // Map: wave w (=tid>>6) handles rowset w, lanes 0..ACOLS-1. 186 tasks, one pass.
    constexpr float inv9 = 1.0f / 9.0f;
    {
        int rs = tid >> 6;
        int sl = tid & 63;
        if (rs < RSETS && sl < ACOLS) {
            int a  = min(max(c0 + sl, 0), A_W - 1);  // A-col this slot represents
            int bs = a - c0;                          // slots bs..bs+2 hold cols a..a+2
            float4 hx  = f4add(f4add(vs[rs][0][bs], vs[rs][0][bs + 1]), vs[rs][0][bs + 2]);
            float4 hy  = f4add(f4add(vs[rs][1][bs], vs[rs][1][bs + 1]), vs[rs][1][bs + 2]);
            float4 hxy = f4add(f4add(vs[rs][2][bs], vs[rs][2][bs + 1]), vs[rs][2][bs + 2]);
            float4 hxx = f4add(f4add(vs[rs][3][bs], vs[rs][3][bs + 1]), vs[rs][3][bs + 2]);
            float4 mx  = f4scale(hx, inv9);
            float4 my  = f4scale(hy, inv9);
            float4 cov = f4sub(f4scale(hxy, inv9), f4mul(mx, my));
            float4 var = f4sub(f4scale(hxx, inv9), f4mul(mx, mx));
            float4 A = f4mul(cov, f4rcp(make_float4(var.x + EPS_F, var.y + EPS_F,
                                                    var.z + EPS_F, var.w + EPS_F)));
            float4 bb = f4sub(my, f4mul(A, mx));
            sA4[rs][sl] = A;
            sB4[rs][sl] = bb;
        }
    }
    __syncthreads();

    // ---- Phase C: horizontal lerp hoisted (tw, wi row-invariant).
    if (valid) {
        float sw = (w + 0.5f) * sw_scale - 0.5f;
        float fw = floorf(sw);
        float tw = sw - fw;
        int wi = min((int)fw - c0, ACOLS - 2);   // 0..60 for valid lanes

        float4 hA0 = f4lerp(sA4[0][wi], sA4[0][wi + 1], tw);
        float4 hB0 = f4lerp(sB4[0][wi], sB4[0][wi + 1], tw);
        float4 hA1 = f4lerp(sA4[1][wi], sA4[1][wi + 1], tw);
        float4 hB1 = f4lerp(sB4[1][wi], sB4[1][wi + 1], tw);
        float4 hA2 = f4lerp(sA4[2][wi], sA4[2][wi + 1], tw);
        float4 hB2 = f4lerp(sB4[2][wi], sB4[2][wi + 1], tw);

#pragma unroll
        for (int j = 0; j < ROWS; ++j) {
            // t in [0,2): tent weights over the 3 staged rowsets reproduce the
            // clamped vertical lerp exactly (slots hold clamped rows).
            float shj = (hbase + j + 0.5f) * sh_scale - 0.5f;
            float t = shj - (float)R0;
            float w0 = fmaxf(1.f - t, 0.f);
            float w1 = 1.f - fabsf(t - 1.f);
            float w2 = fmaxf(t - 1.f, 0.f);

            float4 aI = f4axpy(w2, hA2, f4axpy(w1, hA1, f4scale(hA0, w0)));
            float4 bI = f4axpy(w2, hB2, f4axpy(w1, hB1, f4scale(hB0, w0)));

            nt_store(f4fma(aI, xr[j], bI), &out[hr_row0 + (size_t)j * HR_W]);
        }
    }
}

extern "C" void kernel_launch(void* const* d_in, const int* in_sizes, int n_in,
                              void* d_out, int out_size, void* d_ws, size_t ws_size,
                              hipStream_t stream) {
    const float4* lr_x = (const float4*)d_in[0];
    const float4* lr_y = (const float4*)d_in[1];
    const float4* hr_x = (const float4*)d_in[2];
    float4* out = (float4*)d_out;

    constexpr int nblocks = BATCH * ROWGRP * NTILES;   // 2 * 216 * 8 = 3456
    fgf_fused5<<<nblocks, 256, 0, stream>>>(lr_x, lr_y, hr_x, out);
}

// Round 2
// 26.387 us; speedup vs baseline: 1.1335x; 1.1335x over previous
//
#include <hip/hip_runtime.h>

// FastGuidedFilter on MI355X — round 8: round-7 geometry, round-6 codegen.
// Round-7 post-mortem: __launch_bounds__(256, 8) flipped the allocator into
// remat/spill mode (VGPR 48->32, WRITE_SIZE +13 MB == one float4/thread of
// scratch spill), which also broke the issue-early hr_x prefetch. The forced
// min-waves was unnecessary: LDS (18432 B) and natural VGPR usage (<=48,
// proven by round 6's identical structure at ROWS=8) already permit
// 8 blocks/CU. This round keeps the round-7 geometry and reverts to plain
// __launch_bounds__(256).
//   Phase A: 3 rowsets x 64 cols vertical 3-tap sums {x,y,xy,xx} -> LDS
//   Phase B: 3 rowsets x 62 cols horizontal 3-tap -> (A,b) -> LDS
//   Phase C: hoisted horizontal lerp -> 3 (A,b) pairs/thread, then per row
//            3-slot tent-weight vertical combine + A*hr + b, nt stores.
// hr_x loads issued before phases A/B (issue-early).
//
// Shapes (NHWC, C=4 => one float4 per pixel):
//   lr_x, lr_y : (2, 270, 480, 4) f32
//   hr_x       : (2, 1080, 1920, 4) f32
//   out        : (2, 1080, 1920, 4) f32

namespace {

constexpr int LR_H = 270, LR_W = 480;
constexpr int A_H  = 268, A_W  = 478;   // VALID 3x3 output grid
constexpr int HR_H = 1080, HR_W = 1920;
constexpr int BATCH = 2;
constexpr float EPS_F = 1e-5f;

constexpr int TILE_W = 240;                 // HR px per block row (1920/240=8 exact)
constexpr int NTILES = HR_W / TILE_W;       // 8, uniform
constexpr int ROWS   = 5;                   // HR rows per block
constexpr int ROWGRP = HR_H / ROWS;         // 216, exact
constexpr int VCOLS  = 64;   // vertical-sum slots (A-cols + 2 taps); power of 2
constexpr int ACOLS  = 62;   // A/b slots (max wi = 60, +1 neighbor)
constexpr int RSETS  = 3;    // A-rowsets staged (5 rows: tent t in [0,2))

using f32x4 = __attribute__((ext_vector_type(4))) float;

__device__ __forceinline__ float4 f4add(float4 a, float4 b) {
    return make_float4(a.x + b.x, a.y + b.y, a.z + b.z, a.w + b.w);
}
__device__ __forceinline__ float4 f4sub(float4 a, float4 b) {
    return make_float4(a.x - b.x, a.y - b.y, a.z - b.z, a.w - b.w);
}
__device__ __forceinline__ float4 f4mul(float4 a, float4 b) {
    return make_float4(a.x * b.x, a.y * b.y, a.z * b.z, a.w * b.w);
}
__device__ __forceinline__ float4 f4scale(float4 a, float s) {
    return make_float4(a.x * s, a.y * s, a.z * s, a.w * s);
}
__device__ __forceinline__ float4 f4fma(float4 a, float4 b, float4 c) {
    return make_float4(fmaf(a.x, b.x, c.x), fmaf(a.y, b.y, c.y),
                       fmaf(a.z, b.z, c.z), fmaf(a.w, b.w, c.w));
}
__device__ __forceinline__ float4 f4lerp(float4 a, float4 b, float t) {
    return make_float4(fmaf(t, b.x - a.x, a.x), fmaf(t, b.y - a.y, a.y),
                       fmaf(t, b.z - a.z, a.z), fmaf(t, b.w - a.w, a.w));
}
// acc += s * v (scalar s)
__device__ __forceinline__ float4 f4axpy(float s, float4 v, float4 acc) {
    return make_float4(fmaf(s, v.x, acc.x), fmaf(s, v.y, acc.y),
                       fmaf(s, v.z, acc.z), fmaf(s, v.w, acc.w));
}
__device__ __forceinline__ float4 f4rcp(float4 a) {
    return make_float4(__builtin_amdgcn_rcpf(a.x), __builtin_amdgcn_rcpf(a.y),
                       __builtin_amdgcn_rcpf(a.z), __builtin_amdgcn_rcpf(a.w));
}
__device__ __forceinline__ void nt_store(float4 v, float4* p) {
    f32x4 rv = {v.x, v.y, v.z, v.w};
    __builtin_nontemporal_store(rv, (f32x4*)p);
}

} // namespace

__global__ __launch_bounds__(256) void
fgf_fused5(const float4* __restrict__ lr_x,
           const float4* __restrict__ lr_y,
           const float4* __restrict__ hr_x,
           float4* __restrict__ out) {
    // [rowset][quantity x,y,xy,xx][col] — column-contiguous => conflict-free
    __shared__ float4 vs[RSETS][4][VCOLS];       // 12288 B
    __shared__ float4 sA4[RSETS][ACOLS];         //  2976 B
    __shared__ float4 sB4[RSETS][ACOLS];         //  2976 B => 18240 B total

    int bid  = blockIdx.x;
    int tile = bid & (NTILES - 1);   // NTILES = 8
    int g    = bid >> 3;
    int rg   = g % ROWGRP;
    int b    = g / ROWGRP;
    int tid  = threadIdx.x;

    // jax.image.resize bilinear (antialias=False): src = (i+0.5)*in/out - 0.5,
    // edge renormalization == index-clamped bilinear.
    constexpr float sh_scale = (float)A_H / (float)HR_H;   // 0.248148
    constexpr float sw_scale = (float)A_W / (float)HR_W;   // 0.248958

    int hbase = rg * ROWS;
    int R0 = (int)floorf((hbase + 0.5f) * sh_scale - 0.5f); // -1 at top edge

    int w_start = tile * TILE_W;
    int c0 = (int)floorf((w_start + 0.5f) * sw_scale - 0.5f); // -1 at left edge

    // ---- Issue hr_x loads early (latency hides under phases A/B).
    int w = w_start + tid;
    bool valid = (tid < TILE_W);
    size_t hr_row0 = ((size_t)b * HR_H + hbase) * (size_t)HR_W + w;
    float4 xr[ROWS];
#pragma unroll
    for (int j = 0; j < ROWS; ++j) {
        xr[j] = valid ? hr_x[hr_row0 + (size_t)j * HR_W]
                      : make_float4(0.f, 0.f, 0.f, 0.f);
    }

    // ---- Phase A: vertical 3-tap sums, RSETS x VCOLS = 192 tasks, one pass.
    if (tid < RSETS * VCOLS) {
        int rs = tid >> 6;                             // VCOLS = 64
        int cs = tid & 63;
        int ar = min(max(R0 + rs, 0), A_H - 1);        // A-row this set serves
        int col = min(max(c0 + cs, 0), LR_W - 1);      // lr col (clamped)
        const float4* px = lr_x + ((size_t)b * LR_H + ar) * LR_W + col;
        const float4* py = lr_y + ((size_t)b * LR_H + ar) * LR_W + col;
        float4 sx  = make_float4(0.f, 0.f, 0.f, 0.f);
        float4 sy  = make_float4(0.f, 0.f, 0.f, 0.f);
        float4 sxy = make_float4(0.f, 0.f, 0.f, 0.f);
        float4 sxx = make_float4(0.f, 0.f, 0.f, 0.f);
#pragma unroll
        for (int dy = 0; dy < 3; ++dy) {
            float4 x = px[(size_t)dy * LR_W];
            float4 y = py[(size_t)dy * LR_W];
            sx  = f4add(sx, x);
            sy  = f4add(sy, y);
            sxy = f4fma(x, y, sxy);
            sxx = f4fma(x, x, sxx);
        }
        vs[rs][0][cs] = sx;
        vs[rs][1][cs] = sy;
        vs[rs][2][cs] = sxy;
        vs[rs][3][cs] = sxx;
    }
    __syncthreads();

    // ---- Phase B: horizontal 3-tap -> A,b per rowset.
    // Map: wave w (=tid>>6) handles rowset w, lanes 0..ACOLS-1. 186 tasks, one pass.
    constexpr float inv9 = 1.0f / 9.0f;
    {
        int rs = tid >> 6;
        int sl = tid & 63;
        if (rs < RSETS && sl < ACOLS) {
            int a  = min(max(c0 + sl, 0), A_W - 1);  // A-col this slot represents
            int bs = a - c0;                          // slots bs..bs+2 hold cols a..a+2
            float4 hx  = f4add(f4add(vs[rs][0][bs], vs[rs][0][bs + 1]), vs[rs][0][bs + 2]);
            float4 hy  = f4add(f4add(vs[rs][1][bs], vs[rs][1][bs + 1]), vs[rs][1][bs + 2]);
            float4 hxy = f4add(f4add(vs[rs][2][bs], vs[rs][2][bs + 1]), vs[rs][2][bs + 2]);
            float4 hxx = f4add(f4add(vs[rs][3][bs], vs[rs][3][bs + 1]), vs[rs][3][bs + 2]);
            float4 mx  = f4scale(hx, inv9);
            float4 my  = f4scale(hy, inv9);
            float4 cov = f4sub(f4scale(hxy, inv9), f4mul(mx, my));
            float4 var = f4sub(f4scale(hxx, inv9), f4mul(mx, mx));
            float4 A = f4mul(cov, f4rcp(make_float4(var.x + EPS_F, var.y + EPS_F,
                                                    var.z + EPS_F, var.w + EPS_F)));
            float4 bb = f4sub(my, f4mul(A, mx));
            sA4[rs][sl] = A;
            sB4[rs][sl] = bb;
        }
    }
    __syncthreads();

    // ---- Phase C: horizontal lerp hoisted (tw, wi row-invariant).
    if (valid) {
        float sw = (w + 0.5f) * sw_scale - 0.5f;
        float fw = floorf(sw);
        float tw = sw - fw;
        int wi = min((int)fw - c0, ACOLS - 2);   // 0..60 for valid lanes

        float4 hA0 = f4lerp(sA4[0][wi], sA4[0][wi + 1], tw);
        float4 hB0 = f4lerp(sB4[0][wi], sB4[0][wi + 1], tw);
        float4 hA1 = f4lerp(sA4[1][wi], sA4[1][wi + 1], tw);
        float4 hB1 = f4lerp(sB4[1][wi], sB4[1][wi + 1], tw);
        float4 hA2 = f4lerp(sA4[2][wi], sA4[2][wi + 1], tw);
        float4 hB2 = f4lerp(sB4[2][wi], sB4[2][wi + 1], tw);

#pragma unroll
        for (int j = 0; j < ROWS; ++j) {
            // t in [0,2): tent weights over the 3 staged rowsets reproduce the
            // clamped vertical lerp exactly (slots hold clamped rows).
            float shj = (hbase + j + 0.5f) * sh_scale - 0.5f;
            float t = shj - (float)R0;
            float w0 = fmaxf(1.f - t, 0.f);
            float w1 = 1.f - fabsf(t - 1.f);
            float w2 = fmaxf(t - 1.f, 0.f);

            float4 aI = f4axpy(w2, hA2, f4axpy(w1, hA1, f4scale(hA0, w0)));
            float4 bI = f4axpy(w2, hB2, f4axpy(w1, hB1, f4scale(hB0, w0)));

            nt_store(f4fma(aI, xr[j], bI), &out[hr_row0 + (size_t)j * HR_W]);
        }
    }
}

extern "C" void kernel_launch(void* const* d_in, const int* in_sizes, int n_in,
                              void* d_out, int out_size, void* d_ws, size_t ws_size,
                              hipStream_t stream) {
    const float4* lr_x = (const float4*)d_in[0];
    const float4* lr_y = (const float4*)d_in[1];
    const float4* hr_x = (const float4*)d_in[2];
    float4* out = (float4*)d_out;

    constexpr int nblocks = BATCH * ROWGRP * NTILES;   // 2 * 216 * 8 = 3456
    fgf_fused5<<<nblocks, 256, 0, stream>>>(lr_x, lr_y, hr_x, out);
}